// Round 1
// baseline (1190.870 us; speedup 1.0000x reference)
//
#include <hip/hip_runtime.h>
#include <cstddef>

#define SEQ 2048
#define DM 1024
#define HD 64

// ---------------------------------------------------------------------------
// C[M,N] = A[M,K] @ B[N,K]^T   (fp32, 64x64 tile, BK=16, 4x4 per thread)
// LDS staged transposed: As[k][m], Bs[k][n], pad to 68 so float4 reads stay
// 16B-aligned and store banks spread (2-way on 32 banks = free).
// ---------------------------------------------------------------------------
__global__ __launch_bounds__(256) void gemm_nt(const float* __restrict__ A,
                                               const float* __restrict__ B,
                                               float* __restrict__ C,
                                               int M, int N, int K) {
  __shared__ float As[16][68];
  __shared__ float Bs[16][68];
  const int tx = threadIdx.x & 15;
  const int ty = threadIdx.x >> 4;
  const int bm = blockIdx.y << 6;
  const int bn = blockIdx.x << 6;
  const int lrow = threadIdx.x >> 2;        // 0..63 (tile row)
  const int lcol = (threadIdx.x & 3) << 2;  // 0,4,8,12 (k offset)
  const float* Ap = A + (size_t)(bm + lrow) * K + lcol;
  const float* Bp = B + (size_t)(bn + lrow) * K + lcol;
  float acc[4][4] = {{0.f}};
  for (int k0 = 0; k0 < K; k0 += 16) {
    const float4 a = *(const float4*)(Ap + k0);
    const float4 b = *(const float4*)(Bp + k0);
    __syncthreads();  // previous iteration done reading LDS
    As[lcol + 0][lrow] = a.x; As[lcol + 1][lrow] = a.y;
    As[lcol + 2][lrow] = a.z; As[lcol + 3][lrow] = a.w;
    Bs[lcol + 0][lrow] = b.x; Bs[lcol + 1][lrow] = b.y;
    Bs[lcol + 2][lrow] = b.z; Bs[lcol + 3][lrow] = b.w;
    __syncthreads();
#pragma unroll
    for (int kk = 0; kk < 16; ++kk) {
      const float4 av = *(const float4*)&As[kk][ty << 2];
      const float4 bv = *(const float4*)&Bs[kk][tx << 2];
      const float af[4] = {av.x, av.y, av.z, av.w};
      const float bf[4] = {bv.x, bv.y, bv.z, bv.w};
#pragma unroll
      for (int i = 0; i < 4; ++i)
#pragma unroll
        for (int j = 0; j < 4; ++j)
          acc[i][j] = fmaf(af[i], bf[j], acc[i][j]);
    }
  }
  float* Cp = C + (size_t)(bm + (ty << 2)) * N + bn + (tx << 2);
#pragma unroll
  for (int i = 0; i < 4; ++i) {
    *(float4*)(Cp + (size_t)i * N) =
        make_float4(acc[i][0], acc[i][1], acc[i][2], acc[i][3]);
  }
}

// ---------------------------------------------------------------------------
// Flash-style attention, fp32.
// Q/K/V layout: [b*SEQ + s][DM], head h occupies columns h*HD .. h*HD+63.
// One block per (b, h, 64-query tile): grid = 2*16*32 = 1024, 256 threads.
// LDS: Qs[d][q], Vs[k][d] (stride 68), KS buffer aliased: K-view [d][k]
// stride 68 during score compute, S-view [q][k] stride 65 afterwards
// (stride 65 -> conflict-free row scans in the softmax passes).
// ---------------------------------------------------------------------------
__global__ __launch_bounds__(256) void attn_kernel(const float* __restrict__ Q,
                                                   const float* __restrict__ Km,
                                                   const float* __restrict__ Vm,
                                                   float* __restrict__ O) {
  __shared__ float Qs[64][68];
  __shared__ float Vs[64][68];
  __shared__ float KSbuf[64 * 68];  // aliased K-tile / score-tile
  __shared__ float mrow[64], lsum[64], arow[64];
  __shared__ float red[64][4];
#define KSv(d, k) KSbuf[(d) * 68 + (k)]
#define SSv(q, k) KSbuf[(q) * 65 + (k)]

  const int t = threadIdx.x;
  const int tx = t & 15;
  const int ty = t >> 4;
  const int blk = blockIdx.x;
  const int qt = blk & 31;
  const int h = (blk >> 5) & 15;
  const int b = blk >> 9;
  const size_t base = (size_t)b * SEQ * DM + (size_t)h * HD;
  const float* Qp = Q + base + (size_t)qt * 64 * DM;

  const int lrow = t >> 2;        // 0..63
  const int lcol = (t & 3) << 2;  // 0,4,8,12

  // stage Q transposed: Qs[d][q]
#pragma unroll
  for (int dd = 0; dd < 64; dd += 16) {
    const float4 qv = *(const float4*)(Qp + (size_t)lrow * DM + dd + lcol);
    Qs[dd + lcol + 0][lrow] = qv.x;
    Qs[dd + lcol + 1][lrow] = qv.y;
    Qs[dd + lcol + 2][lrow] = qv.z;
    Qs[dd + lcol + 3][lrow] = qv.w;
  }
  if (t < 64) { mrow[t] = -1e30f; lsum[t] = 0.0f; }

  float acc[4][4] = {{0.f}};
  const int r = t >> 2;         // softmax row handled by this thread
  const int cq = (t & 3) << 4;  // 16-col segment within the row

  for (int kt = 0; kt < 32; ++kt) {
    const float* Kp = Km + base + (size_t)(kt * 64) * DM;
    const float* Vp = Vm + base + (size_t)(kt * 64) * DM;
    float4 kv[4], vv[4];
#pragma unroll
    for (int ii = 0; ii < 4; ++ii) {
      const int dd = ii * 16;
      kv[ii] = *(const float4*)(Kp + (size_t)lrow * DM + dd + lcol);
      vv[ii] = *(const float4*)(Vp + (size_t)lrow * DM + dd + lcol);
    }
    __syncthreads();  // prev iter done reading KS/Vs
#pragma unroll
    for (int ii = 0; ii < 4; ++ii) {
      const int dd = ii * 16;
      KSv(dd + lcol + 0, lrow) = kv[ii].x;
      KSv(dd + lcol + 1, lrow) = kv[ii].y;
      KSv(dd + lcol + 2, lrow) = kv[ii].z;
      KSv(dd + lcol + 3, lrow) = kv[ii].w;
      *(float4*)&Vs[lrow][dd + lcol] = vv[ii];
    }
    __syncthreads();

    // scores: s[i][j] = sum_d Qs[d][ty*4+i] * K[d][tx*4+j]
    float s[4][4] = {{0.f}};
#pragma unroll
    for (int d = 0; d < 64; ++d) {
      const float4 qv = *(const float4*)&Qs[d][ty << 2];
      const float4 kk = *(const float4*)&KSv(d, tx << 2);
      const float qa[4] = {qv.x, qv.y, qv.z, qv.w};
      const float kb[4] = {kk.x, kk.y, kk.z, kk.w};
#pragma unroll
      for (int i = 0; i < 4; ++i)
#pragma unroll
        for (int j = 0; j < 4; ++j)
          s[i][j] = fmaf(qa[i], kb[j], s[i][j]);
    }
    __syncthreads();  // everyone done reading K-view before aliasing as S
#pragma unroll
    for (int i = 0; i < 4; ++i)
#pragma unroll
      for (int j = 0; j < 4; ++j)
        SSv((ty << 2) + i, (tx << 2) + j) = s[i][j] * 0.03125f;
    __syncthreads();

    // online softmax, 4 threads per row
    float mx = -1e30f;
#pragma unroll
    for (int j = 0; j < 16; ++j) mx = fmaxf(mx, SSv(r, cq + j));
    red[r][t & 3] = mx;
    __syncthreads();
    if ((t & 3) == 0) {
      float nm = fmaxf(fmaxf(red[r][0], red[r][1]), fmaxf(red[r][2], red[r][3]));
      nm = fmaxf(nm, mrow[r]);
      arow[r] = __expf(mrow[r] - nm);
      mrow[r] = nm;
    }
    __syncthreads();
    const float nm = mrow[r];
    float ps = 0.f;
#pragma unroll
    for (int j = 0; j < 16; ++j) {
      const float p = __expf(SSv(r, cq + j) - nm);
      SSv(r, cq + j) = p;
      ps += p;
    }
    red[r][t & 3] = ps;
    __syncthreads();
    if ((t & 3) == 0)
      lsum[r] = lsum[r] * arow[r] + (red[r][0] + red[r][1] + red[r][2] + red[r][3]);

    // PV: acc[i][j] = acc*alpha + sum_k P[q][k] * V[k][d]
#pragma unroll
    for (int i = 0; i < 4; ++i) {
      const float al = arow[(ty << 2) + i];
#pragma unroll
      for (int j = 0; j < 4; ++j) acc[i][j] *= al;
    }
#pragma unroll
    for (int k = 0; k < 64; ++k) {
      const float4 v4 = *(const float4*)&Vs[k][tx << 2];
      const float vb[4] = {v4.x, v4.y, v4.z, v4.w};
      const float pa[4] = {SSv((ty << 2) + 0, k), SSv((ty << 2) + 1, k),
                           SSv((ty << 2) + 2, k), SSv((ty << 2) + 3, k)};
#pragma unroll
      for (int i = 0; i < 4; ++i)
#pragma unroll
        for (int j = 0; j < 4; ++j)
          acc[i][j] = fmaf(pa[i], vb[j], acc[i][j]);
    }
  }
  __syncthreads();  // lsum final values visible to all threads

  float* Op = O + base + (size_t)qt * 64 * DM;
#pragma unroll
  for (int i = 0; i < 4; ++i) {
    const float inv = 1.0f / lsum[(ty << 2) + i];
    *(float4*)(Op + (size_t)((ty << 2) + i) * DM + (tx << 2)) =
        make_float4(acc[i][0] * inv, acc[i][1] * inv, acc[i][2] * inv,
                    acc[i][3] * inv);
  }
#undef KSv
#undef SSv
}

extern "C" void kernel_launch(void* const* d_in, const int* in_sizes, int n_in,
                              void* d_out, int out_size, void* d_ws, size_t ws_size,
                              hipStream_t stream) {
  const float* x  = (const float*)d_in[0];
  const float* Wq = (const float*)d_in[1];
  const float* Wk = (const float*)d_in[2];
  const float* Wv = (const float*)d_in[3];
  const float* Wo = (const float*)d_in[4];
  float* out = (float*)d_out;

  const int M = 2 * SEQ;  // 4096 rows
  float* Qb = (float*)d_ws;
  float* Kb = Qb + (size_t)M * DM;
  float* Vb = Kb + (size_t)M * DM;
  float* Cb = Vb + (size_t)M * DM;  // 64 MB total fp32 workspace

  dim3 blk(256);
  dim3 gg(DM / 64, M / 64);  // (16, 64)
  gemm_nt<<<gg, blk, 0, stream>>>(x, Wq, Qb, M, DM, DM);
  gemm_nt<<<gg, blk, 0, stream>>>(x, Wk, Kb, M, DM, DM);
  gemm_nt<<<gg, blk, 0, stream>>>(x, Wv, Vb, M, DM, DM);
  attn_kernel<<<dim3(2 * 16 * (SEQ / 64)), blk, 0, stream>>>(Qb, Kb, Vb, Cb);
  gemm_nt<<<gg, blk, 0, stream>>>(Cb, Wo, out, M, DM, DM);
}

// Round 2
// 281.319 us; speedup vs baseline: 4.2332x; 4.2332x over previous
//
#include <hip/hip_runtime.h>
#include <cstddef>
#include <cstdint>

#define SEQ 2048
#define DM 1024
#define NH 16
#define HD 64

typedef __attribute__((ext_vector_type(8))) short bf16x8;
typedef __attribute__((ext_vector_type(4))) float f32x4;

__device__ __forceinline__ short f2bf(float f) {
  union { float f; unsigned u; } v; v.f = f;
  unsigned r = v.u + 0x7fffu + ((v.u >> 16) & 1u);
  return (short)(r >> 16);
}

__global__ __launch_bounds__(256) void cast_kernel(const float* __restrict__ in,
                                                   short* __restrict__ out, int n4) {
  int i = blockIdx.x * 256 + threadIdx.x;
  if (i < n4) {
    float4 v = ((const float4*)in)[i];
    short4 o;
    o.x = f2bf(v.x); o.y = f2bf(v.y); o.z = f2bf(v.z); o.w = f2bf(v.w);
    ((short4*)out)[i] = o;
  }
}

__device__ __forceinline__ void gload16(const short* g, short* lds) {
  __builtin_amdgcn_global_load_lds((const __attribute__((address_space(1))) void*)g,
                                   (__attribute__((address_space(3))) void*)lds,
                                   16, 0, 0);
}

// ---------------------------------------------------------------------------
// bf16 GEMM mainloop: C[128,128] tile of A[M,K] @ B[N,K]^T.
// m97 structure: BK=32, global_load_lds 16B, unpadded LDS [128][32],
// 4 waves, each 64x64 via 4x4 MFMA 16x16x32, fp32 accum.
// A/B pre-offset to the block's first row.
// ---------------------------------------------------------------------------
__device__ __forceinline__ void gemm_tile(const short* __restrict__ A,
                                          const short* __restrict__ B,
                                          short* As, short* Bs,
                                          int K, f32x4 acc[4][4]) {
  const int t = threadIdx.x;
  const int lane = t & 63;
  const int w = t >> 6;
  const int wm = (w & 1) << 6, wn = (w >> 1) << 6;
  const int srow = lane >> 2, scol = lane & 3;
  const int fr = lane & 15, q = lane >> 4;
  for (int k0 = 0; k0 < K; k0 += 32) {
    __syncthreads();  // all waves done reading previous tiles
#pragma unroll
    for (int c = 0; c < 2; ++c) {
      const int chunk = (w << 1) + c;           // 8 chunks of 16 rows
      const int row = (chunk << 4) + srow;
      gload16(A + (size_t)row * K + k0 + (scol << 3), As + (chunk << 9));
      gload16(B + (size_t)row * K + k0 + (scol << 3), Bs + (chunk << 9));
    }
    __syncthreads();  // drains vmcnt -> LDS visible
    bf16x8 af[4], bfr[4];
#pragma unroll
    for (int i = 0; i < 4; ++i)
      af[i] = *(const bf16x8*)(As + (wm + (i << 4) + fr) * 32 + (q << 3));
#pragma unroll
    for (int j = 0; j < 4; ++j)
      bfr[j] = *(const bf16x8*)(Bs + (wn + (j << 4) + fr) * 32 + (q << 3));
#pragma unroll
    for (int i = 0; i < 4; ++i)
#pragma unroll
      for (int j = 0; j < 4; ++j)
        acc[i][j] = __builtin_amdgcn_mfma_f32_16x16x32_bf16(af[i], bfr[j],
                                                            acc[i][j], 0, 0, 0);
  }
}

// Fused QKV projection. blockIdx.x: 0..23 -> which = x>>3 (0:Q 1:K 2:V),
// bn = (x&7)*128. Q/K stored bf16 [4096][1024]; V stored transposed
// per head: Vtg[b][h][d][s] so attention PV B-frags are k-contiguous.
__global__ __launch_bounds__(256) void gemm_qkv(
    const short* __restrict__ xb, const short* __restrict__ Wqb,
    const short* __restrict__ Wkb, const short* __restrict__ Wvb,
    short* __restrict__ Qb, short* __restrict__ Kb, short* __restrict__ Vtg) {
  __shared__ short As[128 * 32];
  __shared__ short Bs[128 * 32];
  const int which = blockIdx.x >> 3;
  const int bn = (blockIdx.x & 7) << 7;
  const int bm = blockIdx.y << 7;
  const short* B = (which == 0) ? Wqb : (which == 1) ? Wkb : Wvb;
  f32x4 acc[4][4] = {};
  gemm_tile(xb + (size_t)bm * DM, B + (size_t)bn * DM, As, Bs, DM, acc);
  const int lane = threadIdx.x & 63, w = threadIdx.x >> 6;
  const int wm = (w & 1) << 6, wn = (w >> 1) << 6;
  const int col = lane & 15, q = lane >> 4;
  if (which < 2) {
    short* C = (which == 0) ? Qb : Kb;
#pragma unroll
    for (int i = 0; i < 4; ++i) {
      const int m = bm + wm + (i << 4) + (q << 2);
#pragma unroll
      for (int j = 0; j < 4; ++j) {
        const int n = bn + wn + (j << 4) + col;
#pragma unroll
        for (int r = 0; r < 4; ++r)
          C[(size_t)(m + r) * DM + n] = f2bf(acc[i][j][r]);
      }
    }
  } else {
#pragma unroll
    for (int i = 0; i < 4; ++i) {
      const int m = bm + wm + (i << 4) + (q << 2);
      const int b = m >> 11, s = m & 2047;  // 4 consecutive s per lane
#pragma unroll
      for (int j = 0; j < 4; ++j) {
        const int n = bn + wn + (j << 4) + col;
        const int h = n >> 6, d = n & 63;
        short4 o;
        o.x = f2bf(acc[i][j][0]); o.y = f2bf(acc[i][j][1]);
        o.z = f2bf(acc[i][j][2]); o.w = f2bf(acc[i][j][3]);
        *(short4*)(Vtg + (((size_t)(b * NH + h) * HD + d) * SEQ + s)) = o;
      }
    }
  }
}

// Final projection: out fp32 = Ctx(bf16) @ Wo^T(bf16)
__global__ __launch_bounds__(256) void gemm_out(const short* __restrict__ Ab,
                                                const short* __restrict__ Wob,
                                                float* __restrict__ out) {
  __shared__ short As[128 * 32];
  __shared__ short Bs[128 * 32];
  const int bn = blockIdx.x << 7, bm = blockIdx.y << 7;
  f32x4 acc[4][4] = {};
  gemm_tile(Ab + (size_t)bm * DM, Wob + (size_t)bn * DM, As, Bs, DM, acc);
  const int lane = threadIdx.x & 63, w = threadIdx.x >> 6;
  const int wm = (w & 1) << 6, wn = (w >> 1) << 6;
  const int col = lane & 15, q = lane >> 4;
#pragma unroll
  for (int i = 0; i < 4; ++i) {
    const int m = bm + wm + (i << 4) + (q << 2);
#pragma unroll
    for (int j = 0; j < 4; ++j) {
      const int n = bn + wn + (j << 4) + col;
#pragma unroll
      for (int r = 0; r < 4; ++r)
        out[(size_t)(m + r) * DM + n] = acc[i][j][r];
    }
  }
}

// ---------------------------------------------------------------------------
// MFMA flash attention. Block = (b, h, 64-query tile); 4 waves, wave w owns
// q-rows 16w..16w+15 -> softmax state is quad-local (shfl_xor 1/2/4/8).
// LDS tiles stride 72 (144 B, 16B-aligned) to spread banks.
// P goes C-layout -> LDS -> A-layout (wave-private rows, no barrier needed).
// ---------------------------------------------------------------------------
__global__ __launch_bounds__(256) void attn_mfma(const short* __restrict__ Qb,
                                                 const short* __restrict__ Kb,
                                                 const short* __restrict__ Vtg,
                                                 short* __restrict__ Ctx) {
  __shared__ short Qs[64 * 72];
  __shared__ short Ks[64 * 72];
  __shared__ short Vs[64 * 72];  // V^T tile: [d][k]
  __shared__ short Ps[64 * 72];  // P: [q][k], wave-private 16-row bands
  const int t = threadIdx.x, lane = t & 63, w = t >> 6;
  const int qt = blockIdx.x & 31, h = (blockIdx.x >> 5) & 15, b = blockIdx.x >> 9;
  const short* Qp = Qb + (size_t)(b * SEQ + qt * 64) * DM + h * HD;
  const short* Kp = Kb + (size_t)b * SEQ * DM + h * HD;
  const short* Vp = Vtg + (size_t)(b * NH + h) * HD * SEQ;
  const int col = lane & 15, q = lane >> 4;

  for (int ch = t; ch < 512; ch += 256) {
    const int row = ch >> 3, c8 = (ch & 7) << 3;
    *(bf16x8*)(Qs + row * 72 + c8) = *(const bf16x8*)(Qp + (size_t)row * DM + c8);
  }

  f32x4 acc[4] = {};  // ctx accum, 4 d-tiles (C-layout)
  float mrun[4], lrun[4];
#pragma unroll
  for (int r = 0; r < 4; ++r) { mrun[r] = -1e30f; lrun[r] = 0.f; }
  const float c1 = 1.44269504089f / 32.0f;  // log2(e)/sqrt(d_model)

  for (int kt = 0; kt < 32; ++kt) {
    __syncthreads();  // all waves done with previous K/V tiles
    for (int ch = t; ch < 512; ch += 256) {
      const int row = ch >> 3, c8 = (ch & 7) << 3;
      *(bf16x8*)(Ks + row * 72 + c8) =
          *(const bf16x8*)(Kp + (size_t)(kt * 64 + row) * DM + c8);
      *(bf16x8*)(Vs + row * 72 + c8) =
          *(const bf16x8*)(Vp + (size_t)row * SEQ + kt * 64 + c8);
    }
    __syncthreads();

    // S = Q K^T  (raw, scale folded into softmax)
    bf16x8 aq0 = *(const bf16x8*)(Qs + ((w << 4) + col) * 72 + (q << 3));
    bf16x8 aq1 = *(const bf16x8*)(Qs + ((w << 4) + col) * 72 + 32 + (q << 3));
    f32x4 s[4];
#pragma unroll
    for (int j = 0; j < 4; ++j) {
      f32x4 z = {0.f, 0.f, 0.f, 0.f};
      bf16x8 bk0 = *(const bf16x8*)(Ks + ((j << 4) + col) * 72 + (q << 3));
      bf16x8 bk1 = *(const bf16x8*)(Ks + ((j << 4) + col) * 72 + 32 + (q << 3));
      z = __builtin_amdgcn_mfma_f32_16x16x32_bf16(aq0, bk0, z, 0, 0, 0);
      z = __builtin_amdgcn_mfma_f32_16x16x32_bf16(aq1, bk1, z, 0, 0, 0);
      s[j] = z;
    }

    // online softmax (base-2), rows q*4+r, quad-local reductions
    float p[4][4];
    float alpha[4];
#pragma unroll
    for (int r = 0; r < 4; ++r) {
      float mx = -1e30f;
#pragma unroll
      for (int j = 0; j < 4; ++j) mx = fmaxf(mx, s[j][r]);
      mx = fmaxf(mx, __shfl_xor(mx, 1));
      mx = fmaxf(mx, __shfl_xor(mx, 2));
      mx = fmaxf(mx, __shfl_xor(mx, 4));
      mx = fmaxf(mx, __shfl_xor(mx, 8));
      mx *= c1;
      const float mnew = fmaxf(mrun[r], mx);
      alpha[r] = __builtin_amdgcn_exp2f(mrun[r] - mnew);
      mrun[r] = mnew;
      float rs = 0.f;
#pragma unroll
      for (int j = 0; j < 4; ++j) {
        const float pv = __builtin_amdgcn_exp2f(s[j][r] * c1 - mnew);
        p[j][r] = pv;
        rs += pv;
      }
      rs += __shfl_xor(rs, 1);
      rs += __shfl_xor(rs, 2);
      rs += __shfl_xor(rs, 4);
      rs += __shfl_xor(rs, 8);
      lrun[r] = lrun[r] * alpha[r] + rs;
      acc[0][r] *= alpha[r]; acc[1][r] *= alpha[r];
      acc[2][r] *= alpha[r]; acc[3][r] *= alpha[r];
    }

    // P: C-layout -> LDS (wave-private rows)
#pragma unroll
    for (int j = 0; j < 4; ++j)
#pragma unroll
      for (int r = 0; r < 4; ++r)
        Ps[((w << 4) + (q << 2) + r) * 72 + (j << 4) + col] = f2bf(p[j][r]);

    // ctx += P V
    bf16x8 ap0 = *(const bf16x8*)(Ps + ((w << 4) + col) * 72 + (q << 3));
    bf16x8 ap1 = *(const bf16x8*)(Ps + ((w << 4) + col) * 72 + 32 + (q << 3));
#pragma unroll
    for (int dt = 0; dt < 4; ++dt) {
      bf16x8 bv0 = *(const bf16x8*)(Vs + ((dt << 4) + col) * 72 + (q << 3));
      bf16x8 bv1 = *(const bf16x8*)(Vs + ((dt << 4) + col) * 72 + 32 + (q << 3));
      acc[dt] = __builtin_amdgcn_mfma_f32_16x16x32_bf16(ap0, bv0, acc[dt], 0, 0, 0);
      acc[dt] = __builtin_amdgcn_mfma_f32_16x16x32_bf16(ap1, bv1, acc[dt], 0, 0, 0);
    }
  }

  const int mrow0 = qt * 64 + (w << 4) + (q << 2);
#pragma unroll
  for (int r = 0; r < 4; ++r) {
    const float inv = __builtin_amdgcn_rcpf(lrun[r]);
    const size_t rowbase = (size_t)(b * SEQ + mrow0 + r) * DM + h * HD;
#pragma unroll
    for (int dt = 0; dt < 4; ++dt)
      Ctx[rowbase + (dt << 4) + col] = f2bf(acc[dt][r] * inv);
  }
}

extern "C" void kernel_launch(void* const* d_in, const int* in_sizes, int n_in,
                              void* d_out, int out_size, void* d_ws, size_t ws_size,
                              hipStream_t stream) {
  const float* x  = (const float*)d_in[0];
  const float* Wq = (const float*)d_in[1];
  const float* Wk = (const float*)d_in[2];
  const float* Wv = (const float*)d_in[3];
  const float* Wo = (const float*)d_in[4];

  char* ws = (char*)d_ws;
  short* xb  = (short*)(ws);                      // 8 MB
  short* Wqb = (short*)(ws + (8u << 20));         // 2 MB
  short* Wkb = (short*)(ws + (10u << 20));
  short* Wvb = (short*)(ws + (12u << 20));
  short* Wob = (short*)(ws + (14u << 20));
  short* Qb  = (short*)(ws + (16u << 20));        // 8 MB
  short* Kb  = (short*)(ws + (24u << 20));        // 8 MB
  short* Vtg = (short*)(ws + (32u << 20));        // 8 MB  [b][h][d][s]
  short* Ctx = (short*)(ws + (40u << 20));        // 8 MB -> 48 MB total

  cast_kernel<<<4096, 256, 0, stream>>>(x, xb, 1048576);
  cast_kernel<<<1024, 256, 0, stream>>>(Wq, Wqb, 262144);
  cast_kernel<<<1024, 256, 0, stream>>>(Wk, Wkb, 262144);
  cast_kernel<<<1024, 256, 0, stream>>>(Wv, Wvb, 262144);
  cast_kernel<<<1024, 256, 0, stream>>>(Wo, Wob, 262144);

  gemm_qkv<<<dim3(24, 32), 256, 0, stream>>>(xb, Wqb, Wkb, Wvb, Qb, Kb, Vtg);
  attn_mfma<<<dim3(2 * NH * (SEQ / 64)), 256, 0, stream>>>(Qb, Kb, Vtg, Ctx);
  gemm_out<<<dim3(8, 32), 256, 0, stream>>>(Ctx, Wob, (float*)d_out);
}

// Round 4
// 203.203 us; speedup vs baseline: 5.8605x; 1.3844x over previous
//
#include <hip/hip_runtime.h>
#include <cstddef>
#include <cstdint>

#define SEQ 2048
#define DM 1024
#define NH 16
#define HD 64

typedef _Float16 f16;
typedef __attribute__((ext_vector_type(8))) _Float16 f16x8;
typedef __attribute__((ext_vector_type(4))) _Float16 f16x4;
typedef __attribute__((ext_vector_type(2))) _Float16 f16x2;
typedef __attribute__((ext_vector_type(2))) __fp16 hf16x2;
typedef __attribute__((ext_vector_type(4))) float f32x4;

__global__ __launch_bounds__(256) void cast_kernel(const float* __restrict__ in,
                                                   f16* __restrict__ out, int n4) {
  int i = blockIdx.x * 256 + threadIdx.x;
  if (i < n4) {
    float4 v = ((const float4*)in)[i];
    f16x4 o = {(f16)v.x, (f16)v.y, (f16)v.z, (f16)v.w};
    ((f16x4*)out)[i] = o;
  }
}

__device__ __forceinline__ void gload16(const void* g, void* lds) {
  __builtin_amdgcn_global_load_lds((const __attribute__((address_space(1))) void*)g,
                                   (__attribute__((address_space(3))) void*)lds,
                                   16, 0, 0);
}

// ---------------------------------------------------------------------------
// f16 GEMM mainloop (m97 structure): C[128,128] tile of A[M,K] @ B[N,K]^T.
// ---------------------------------------------------------------------------
__device__ __forceinline__ void gemm_tile(const f16* __restrict__ A,
                                          const f16* __restrict__ B,
                                          f16* As, f16* Bs,
                                          int K, f32x4 acc[4][4]) {
  const int t = threadIdx.x;
  const int lane = t & 63;
  const int w = t >> 6;
  const int wm = (w & 1) << 6, wn = (w >> 1) << 6;
  const int srow = lane >> 2, scol = lane & 3;
  const int fr = lane & 15, q = lane >> 4;
  for (int k0 = 0; k0 < K; k0 += 32) {
    __syncthreads();
#pragma unroll
    for (int c = 0; c < 2; ++c) {
      const int chunk = (w << 1) + c;
      const int row = (chunk << 4) + srow;
      gload16(A + (size_t)row * K + k0 + (scol << 3), As + (chunk << 9));
      gload16(B + (size_t)row * K + k0 + (scol << 3), Bs + (chunk << 9));
    }
    __syncthreads();
    f16x8 af[4], bfr[4];
#pragma unroll
    for (int i = 0; i < 4; ++i)
      af[i] = *(const f16x8*)(As + (wm + (i << 4) + fr) * 32 + (q << 3));
#pragma unroll
    for (int j = 0; j < 4; ++j)
      bfr[j] = *(const f16x8*)(Bs + (wn + (j << 4) + fr) * 32 + (q << 3));
#pragma unroll
    for (int i = 0; i < 4; ++i)
#pragma unroll
      for (int j = 0; j < 4; ++j)
        acc[i][j] = __builtin_amdgcn_mfma_f32_16x16x32_f16(af[i], bfr[j],
                                                           acc[i][j], 0, 0, 0);
  }
}

// Fused QKV projection. Q pre-scaled by log2(e)/sqrt(d_model) for base-2
// no-max softmax. V stored transposed per head: Vtg[b][h][d][s].
#define QSCALE 0.04508422003f  /* 1.4426950409/32 */
__global__ __launch_bounds__(256) void gemm_qkv(
    const f16* __restrict__ xb, const f16* __restrict__ Wqb,
    const f16* __restrict__ Wkb, const f16* __restrict__ Wvb,
    f16* __restrict__ Qb, f16* __restrict__ Kb, f16* __restrict__ Vtg) {
  __shared__ f16 As[128 * 32];
  __shared__ f16 Bs[128 * 32];
  const int which = blockIdx.x >> 3;
  const int bn = (blockIdx.x & 7) << 7;
  const int bm = blockIdx.y << 7;
  const f16* B = (which == 0) ? Wqb : (which == 1) ? Wkb : Wvb;
  f32x4 acc[4][4] = {};
  gemm_tile(xb + (size_t)bm * DM, B + (size_t)bn * DM, As, Bs, DM, acc);
  const int lane = threadIdx.x & 63, w = threadIdx.x >> 6;
  const int wm = (w & 1) << 6, wn = (w >> 1) << 6;
  const int col = lane & 15, q = lane >> 4;
  if (which < 2) {
    f16* C = (which == 0) ? Qb : Kb;
    const float sc = (which == 0) ? QSCALE : 1.0f;
#pragma unroll
    for (int i = 0; i < 4; ++i) {
      const int m = bm + wm + (i << 4) + (q << 2);
#pragma unroll
      for (int j = 0; j < 4; ++j) {
        const int n = bn + wn + (j << 4) + col;
#pragma unroll
        for (int r = 0; r < 4; ++r)
          C[(size_t)(m + r) * DM + n] = (f16)(acc[i][j][r] * sc);
      }
    }
  } else {
#pragma unroll
    for (int i = 0; i < 4; ++i) {
      const int m = bm + wm + (i << 4) + (q << 2);
      const int b = m >> 11, s = m & 2047;
#pragma unroll
      for (int j = 0; j < 4; ++j) {
        const int n = bn + wn + (j << 4) + col;
        const int h = n >> 6, d = n & 63;
        f16x4 o = {(f16)acc[i][j][0], (f16)acc[i][j][1],
                   (f16)acc[i][j][2], (f16)acc[i][j][3]};
        *(f16x4*)(Vtg + (((size_t)(b * NH + h) * HD + d) * SEQ + s)) = o;
      }
    }
  }
}

__global__ __launch_bounds__(256) void gemm_out(const f16* __restrict__ Ab,
                                                const f16* __restrict__ Wob,
                                                float* __restrict__ out) {
  __shared__ f16 As[128 * 32];
  __shared__ f16 Bs[128 * 32];
  const int bn = blockIdx.x << 7, bm = blockIdx.y << 7;
  f32x4 acc[4][4] = {};
  gemm_tile(Ab + (size_t)bm * DM, Wob + (size_t)bn * DM, As, Bs, DM, acc);
  const int lane = threadIdx.x & 63, w = threadIdx.x >> 6;
  const int wm = (w & 1) << 6, wn = (w >> 1) << 6;
  const int col = lane & 15, q = lane >> 4;
#pragma unroll
  for (int i = 0; i < 4; ++i) {
    const int m = bm + wm + (i << 4) + (q << 2);
#pragma unroll
    for (int j = 0; j < 4; ++j) {
      const int n = bn + wn + (j << 4) + col;
#pragma unroll
      for (int r = 0; r < 4; ++r)
        out[(size_t)(m + r) * DM + n] = acc[i][j][r];
    }
  }
}

// ---------------------------------------------------------------------------
// MFMA flash attention, transposed-score formulation, f16, no-max softmax.
// Block = (b, h, 128-query tile); wave w owns q 32w..32w+31 (2 x 16 q-cols).
// S^T = K.Q^T via 16x16x32; C-layout of S^T (k=quad*4+reg, q=lane&15) IS the
// B-operand layout of mfma_16x16x16 -> exp2 + pack feeds PV directly, P never
// touches LDS. ctx^T accumulated; epilogue transposes via LDS (wave-private).
// K staged via global_load_lds in m97 half-split geometry [2][64][32];
// V^T staged via global_load_lds with XOR-16B swizzle (b64 frag reads land
// 4 lanes/bank-pair = natural throughput, zero excess conflict).
// ---------------------------------------------------------------------------
__global__ __launch_bounds__(256) void attn_mfma(const f16* __restrict__ Qb,
                                                 const f16* __restrict__ Kb,
                                                 const f16* __restrict__ Vtg,
                                                 f16* __restrict__ Ctx) {
  __shared__ f16 smem[8192];           // 16 KB: Ks[0:4096) Vs[4096:8192)
  f16* Ks = smem;                      // [half][64 k-rows][32 d]
  f16* Vs = smem + 4096;               // [half][4 dchunk][16 d-rows][32 k] swz
  const int t = threadIdx.x, lane = t & 63, w = t >> 6;
  const int fr = lane & 15, quad = lane >> 4;
  const int qt16 = blockIdx.x & 15;
  const int h = (blockIdx.x >> 4) & 15, b = blockIdx.x >> 8;

  const size_t qrow0 = (size_t)b * SEQ + qt16 * 128 + w * 32;

  // Q^T B-frags, direct from global (loop-invariant): [qt][half]
  f16x8 Qf[2][2];
#pragma unroll
  for (int qt = 0; qt < 2; ++qt)
#pragma unroll
    for (int hf = 0; hf < 2; ++hf)
      Qf[qt][hf] = *(const f16x8*)(Qb + (qrow0 + qt * 16 + fr) * DM + h * HD +
                                   hf * 32 + (quad << 3));

  // staging source pointers (wave w stages k-rows / d-rows 16w..16w+15)
  const f16* Kg = Kb + ((size_t)b * SEQ + 16 * w + (lane >> 2)) * DM + h * HD +
                  (lane & 3) * 8;
  const f16* Vg = Vtg + (((size_t)(b * NH + h) * HD) + 16 * w + (lane >> 2)) * SEQ +
                  (((lane & 3) ^ ((lane >> 2) & 3)) << 3);
  f16* KsD0 = Ks + w * 512;            // half0 chunk w
  f16* KsD1 = Ks + 2048 + w * 512;     // half1
  f16* VsD0 = Vs + w * 512;
  f16* VsD1 = Vs + 2048 + w * 512;

  f32x4 acc[2][4] = {};                // ctx^T [qt][dtile]
  float lacc[2] = {0.f, 0.f};

  for (int kt = 0; kt < 32; ++kt) {
    const size_t ko = (size_t)kt * 64;
    __syncthreads();                   // all waves done reading prev tiles
    gload16(Kg + ko * DM, KsD0);
    gload16(Kg + ko * DM + 32, KsD1);
    gload16(Vg + ko, VsD0);
    gload16(Vg + ko + 32, VsD1);
    __syncthreads();                   // vmcnt drained -> LDS visible

    // K A-frags [mtile][half]
    f16x8 Kf[4][2];
#pragma unroll
    for (int mt = 0; mt < 4; ++mt)
#pragma unroll
      for (int hf = 0; hf < 2; ++hf)
        Kf[mt][hf] = *(const f16x8*)(Ks + hf * 2048 + (mt * 16 + fr) * 32 +
                                     (quad << 3));

    f16x4 pf[2][4];
#pragma unroll
    for (int qt = 0; qt < 2; ++qt) {
      f32x4 z[4] = {};
#pragma unroll
      for (int mt = 0; mt < 4; ++mt) {
        z[mt] = __builtin_amdgcn_mfma_f32_16x16x32_f16(Kf[mt][0], Qf[qt][0],
                                                       z[mt], 0, 0, 0);
        z[mt] = __builtin_amdgcn_mfma_f32_16x16x32_f16(Kf[mt][1], Qf[qt][1],
                                                       z[mt], 0, 0, 0);
      }
#pragma unroll
      for (int mt = 0; mt < 4; ++mt) {
        const float p0 = __builtin_amdgcn_exp2f(z[mt][0]);
        const float p1 = __builtin_amdgcn_exp2f(z[mt][1]);
        const float p2 = __builtin_amdgcn_exp2f(z[mt][2]);
        const float p3 = __builtin_amdgcn_exp2f(z[mt][3]);
        lacc[qt] += (p0 + p1) + (p2 + p3);
        const f16x2 lo = __builtin_bit_cast(f16x2, __builtin_amdgcn_cvt_pkrtz(p0, p1));
        const f16x2 hi = __builtin_bit_cast(f16x2, __builtin_amdgcn_cvt_pkrtz(p2, p3));
        f16x4 pv; pv.x = lo.x; pv.y = lo.y; pv.z = hi.x; pv.w = hi.y;
        pf[qt][mt] = pv;
      }
    }

    // ctx^T += V^T . P^T
#pragma unroll
    for (int dt = 0; dt < 4; ++dt) {
#pragma unroll
      for (int kc = 0; kc < 4; ++kc) {
        const int gg = (((kc & 1) << 1) + (quad >> 1)) ^ (fr & 3);
        const f16x4 vf = *(const f16x4*)(Vs + ((kc >> 1) * 4 + dt) * 512 +
                                         fr * 32 + (gg << 3) + ((quad & 1) << 2));
#pragma unroll
        for (int qt = 0; qt < 2; ++qt)
          acc[qt][dt] = __builtin_amdgcn_mfma_f32_16x16x16f16(vf, pf[qt][kc],
                                                              acc[qt][dt], 0, 0, 0);
      }
    }
  }

  // l reduction over quads (lanes fr, fr+16, fr+32, fr+48 share a q-col)
  float inv[2];
#pragma unroll
  for (int qt = 0; qt < 2; ++qt) {
    float l = lacc[qt];
    l += __shfl_xor(l, 16);
    l += __shfl_xor(l, 32);
    inv[qt] = __builtin_amdgcn_rcpf(l);
  }

  __syncthreads();  // everyone done with Ks/Vs before epilogue reuse
  f16* T = smem + w * 2048;  // wave-private [32 q][64 d]
#pragma unroll
  for (int qt = 0; qt < 2; ++qt)
#pragma unroll
    for (int dt = 0; dt < 4; ++dt)
#pragma unroll
      for (int r = 0; r < 4; ++r)
        T[(qt * 16 + fr) * 64 + dt * 16 + (quad << 2) + r] =
            (f16)(acc[qt][dt][r] * inv[qt]);
  // same-wave read-back (compiler inserts lgkmcnt wait), coalesced store
#pragma unroll
  for (int p = 0; p < 4; ++p) {
    const int ql = p * 8 + (lane >> 3);
    const f16x8 v = *(const f16x8*)(T + ql * 64 + ((lane & 7) << 3));
    *(f16x8*)(Ctx + (qrow0 + ql) * DM + h * HD + ((lane & 7) << 3)) = v;
  }
}

extern "C" void kernel_launch(void* const* d_in, const int* in_sizes, int n_in,
                              void* d_out, int out_size, void* d_ws, size_t ws_size,
                              hipStream_t stream) {
  const float* x  = (const float*)d_in[0];
  const float* Wq = (const float*)d_in[1];
  const float* Wk = (const float*)d_in[2];
  const float* Wv = (const float*)d_in[3];
  const float* Wo = (const float*)d_in[4];

  char* ws = (char*)d_ws;
  f16* xb  = (f16*)(ws);                    // 8 MB
  f16* Wqb = (f16*)(ws + (8u << 20));       // 2 MB each
  f16* Wkb = (f16*)(ws + (10u << 20));
  f16* Wvb = (f16*)(ws + (12u << 20));
  f16* Wob = (f16*)(ws + (14u << 20));
  f16* Qb  = (f16*)(ws + (16u << 20));      // 8 MB (pre-scaled by log2e/32)
  f16* Kb  = (f16*)(ws + (24u << 20));
  f16* Vtg = (f16*)(ws + (32u << 20));      // [b][h][d][s]
  f16* Ctx = (f16*)(ws + (40u << 20));      // -> 48 MB total

  cast_kernel<<<4096, 256, 0, stream>>>(x, xb, 1048576);
  cast_kernel<<<1024, 256, 0, stream>>>(Wq, Wqb, 262144);
  cast_kernel<<<1024, 256, 0, stream>>>(Wk, Wkb, 262144);
  cast_kernel<<<1024, 256, 0, stream>>>(Wv, Wvb, 262144);
  cast_kernel<<<1024, 256, 0, stream>>>(Wo, Wob, 262144);

  gemm_qkv<<<dim3(24, 32), 256, 0, stream>>>(xb, Wqb, Wkb, Wvb, Qb, Kb, Vtg);
  attn_mfma<<<dim3(2 * NH * (SEQ / 128)), 256, 0, stream>>>(Qb, Kb, Vtg, Ctx);
  gemm_out<<<dim3(8, 32), 256, 0, stream>>>(Ctx, Wob, (float*)d_out);
}